// Round 1
// baseline (12921.674 us; speedup 1.0000x reference)
//
#include <hip/hip_runtime.h>
#include <math.h>

#define D_DIM 2048
#define N_ROWS 4096
#define EPS_DIAG 1e-3f
#define NS_ITERS 18

#define BM 128
#define BN 64
#define BK 32
#define PA 132   // padded LDS leading dim for [BK][BM]
#define PB 68    // padded LDS leading dim for [BK][BN]

// ---------------- column statistics (mean / rstd, ddof=1) ----------------

__global__ __launch_bounds__(256)
void k_colstats(const float* __restrict__ z, float* __restrict__ sum_,
                float* __restrict__ ssq_) {
  const int c = blockIdx.x * 256 + threadIdx.x;        // column
  const int r0 = blockIdx.y * (N_ROWS / 16);
  float s = 0.f, q = 0.f;
#pragma unroll 8
  for (int r = 0; r < N_ROWS / 16; ++r) {
    float v = z[(size_t)(r0 + r) * D_DIM + c];
    s += v;
    q += v * v;
  }
  atomicAdd(&sum_[c], s);
  atomicAdd(&ssq_[c], q);
}

__global__ __launch_bounds__(256)
void k_finalize_stats(float* stat) {
  const int t = blockIdx.x * 256 + threadIdx.x;  // 0..4095 (two inputs x D)
  const int g = t >> 11;
  const int c = t & (D_DIM - 1);
  float* base = stat + g * 2 * D_DIM;
  float s = base[c];
  float q = base[D_DIM + c];
  float mean = s * (1.0f / N_ROWS);
  float var = (q - (float)N_ROWS * mean * mean) * (1.0f / (N_ROWS - 1));
  var = fmaxf(var, 1e-30f);
  base[c] = mean;              // mean overwrites sum slot
  base[D_DIM + c] = 1.0f / sqrtf(var);  // rstd overwrites ssq slot
}

// ---------------- Gram: out = zhat^T zhat + eps*I  (K = N_ROWS) ----------------

__global__ __launch_bounds__(256)
void k_gram(const float* __restrict__ z, const float* __restrict__ mean,
            const float* __restrict__ rstd, float* __restrict__ out) {
  __shared__ float U[BK][PA];
  __shared__ float V[BK][PB];
  const int tid = threadIdx.x;
  const int I = blockIdx.y * BM;
  const int J = blockIdx.x * BN;
  const int tx = tid & 15;
  const int ty = tid >> 4;

  const int uc4 = tid & 31;  // U staging: 32 rows x 32 float4; 4 per thread
  const int ur0 = tid >> 5;  // rows ur0 + 8p
  const int vc4 = tid & 15;  // V staging: 32 rows x 16 float4; 2 per thread
  const int vr0 = tid >> 4;  // rows vr0 + 16p

  const float4 mU = ((const float4*)mean)[(I >> 2) + uc4];
  const float4 rU = ((const float4*)rstd)[(I >> 2) + uc4];
  const float4 mV = ((const float4*)mean)[(J >> 2) + vc4];
  const float4 rV = ((const float4*)rstd)[(J >> 2) + vc4];

  float acc[8][4];
#pragma unroll
  for (int i = 0; i < 8; ++i)
#pragma unroll
    for (int j = 0; j < 4; ++j) acc[i][j] = 0.f;

  for (int k0 = 0; k0 < N_ROWS; k0 += BK) {
#pragma unroll
    for (int p = 0; p < 4; ++p) {
      int rr = ur0 + p * 8;
      float4 v = *(const float4*)(z + (size_t)(k0 + rr) * D_DIM + I + uc4 * 4);
      v.x = (v.x - mU.x) * rU.x;
      v.y = (v.y - mU.y) * rU.y;
      v.z = (v.z - mU.z) * rU.z;
      v.w = (v.w - mU.w) * rU.w;
      *(float4*)&U[rr][uc4 * 4] = v;
    }
#pragma unroll
    for (int p = 0; p < 2; ++p) {
      int rr = vr0 + p * 16;
      float4 v = *(const float4*)(z + (size_t)(k0 + rr) * D_DIM + J + vc4 * 4);
      v.x = (v.x - mV.x) * rV.x;
      v.y = (v.y - mV.y) * rV.y;
      v.z = (v.z - mV.z) * rV.z;
      v.w = (v.w - mV.w) * rV.w;
      *(float4*)&V[rr][vc4 * 4] = v;
    }
    __syncthreads();
#pragma unroll
    for (int kk = 0; kk < BK; ++kk) {
      float4 a0 = *(const float4*)&U[kk][ty * 4];
      float4 a1 = *(const float4*)&U[kk][64 + ty * 4];
      float4 b0 = *(const float4*)&V[kk][tx * 4];
      float av[8] = {a0.x, a0.y, a0.z, a0.w, a1.x, a1.y, a1.z, a1.w};
      float bv[4] = {b0.x, b0.y, b0.z, b0.w};
#pragma unroll
      for (int i = 0; i < 8; ++i)
#pragma unroll
        for (int j = 0; j < 4; ++j) acc[i][j] += av[i] * bv[j];
    }
    __syncthreads();
  }

#pragma unroll
  for (int i = 0; i < 8; ++i) {
    int row = (i < 4) ? (ty * 4 + i) : (64 + ty * 4 + (i - 4));
    int gi = I + row;
    float4 v;
    float* pv = (float*)&v;
#pragma unroll
    for (int j = 0; j < 4; ++j) {
      int gj = J + tx * 4 + j;
      pv[j] = acc[i][j] + ((gi == gj) ? EPS_DIAG : 0.f);
    }
    *(float4*)(out + (size_t)gi * D_DIM + J + tx * 4) = v;
  }
}

// ---------------- square GEMM 2048^3, NN layout ----------------
// MODE 0: C = A*B     MODE 1: C = 3I - A*B     MODE 2: C = 0.5*A*B

template <int MODE>
__global__ __launch_bounds__(256)
void k_gemm(const float* __restrict__ A, const float* __restrict__ B,
            float* __restrict__ C) {
  __shared__ float As[BK][PA];  // As[k][i] (A transposed in LDS)
  __shared__ float Bs[BK][PB];  // Bs[k][j]
  const int tid = threadIdx.x;
  const int I = blockIdx.y * BM;
  const int J = blockIdx.x * BN;
  const int tx = tid & 15;
  const int ty = tid >> 4;

  const int ak4 = tid & 7;   // A staging: 128 rows x 8 float4; 4 per thread
  const int ar0 = tid >> 3;  // rows ar0 + 32p
  const int bk4 = tid & 15;  // B staging: 32 rows x 16 float4; 2 per thread
  const int br0 = tid >> 4;  // rows br0 + 16p

  float acc[8][4];
#pragma unroll
  for (int i = 0; i < 8; ++i)
#pragma unroll
    for (int j = 0; j < 4; ++j) acc[i][j] = 0.f;

  for (int k0 = 0; k0 < D_DIM; k0 += BK) {
#pragma unroll
    for (int p = 0; p < 4; ++p) {
      int r = ar0 + p * 32;
      float4 v = *(const float4*)(A + (size_t)(I + r) * D_DIM + k0 + ak4 * 4);
      As[ak4 * 4 + 0][r] = v.x;
      As[ak4 * 4 + 1][r] = v.y;
      As[ak4 * 4 + 2][r] = v.z;
      As[ak4 * 4 + 3][r] = v.w;
    }
#pragma unroll
    for (int p = 0; p < 2; ++p) {
      int r = br0 + p * 16;
      float4 v = *(const float4*)(B + (size_t)(k0 + r) * D_DIM + J + bk4 * 4);
      *(float4*)&Bs[r][bk4 * 4] = v;
    }
    __syncthreads();
#pragma unroll
    for (int kk = 0; kk < BK; ++kk) {
      float4 a0 = *(const float4*)&As[kk][ty * 4];
      float4 a1 = *(const float4*)&As[kk][64 + ty * 4];
      float4 b0 = *(const float4*)&Bs[kk][tx * 4];
      float av[8] = {a0.x, a0.y, a0.z, a0.w, a1.x, a1.y, a1.z, a1.w};
      float bv[4] = {b0.x, b0.y, b0.z, b0.w};
#pragma unroll
      for (int i = 0; i < 8; ++i)
#pragma unroll
        for (int j = 0; j < 4; ++j) acc[i][j] += av[i] * bv[j];
    }
    __syncthreads();
  }

#pragma unroll
  for (int i = 0; i < 8; ++i) {
    int row = (i < 4) ? (ty * 4 + i) : (64 + ty * 4 + (i - 4));
    int gi = I + row;
    float4 v;
    float* pv = (float*)&v;
#pragma unroll
    for (int j = 0; j < 4; ++j) {
      int gj = J + tx * 4 + j;
      float val = acc[i][j];
      if (MODE == 1) val = ((gi == gj) ? 3.0f : 0.0f) - val;
      if (MODE == 2) val = 0.5f * val;
      pv[j] = val;
    }
    *(float4*)(C + (size_t)gi * D_DIM + J + tx * 4) = v;
  }
}

// ---------------- small utility kernels ----------------

__global__ __launch_bounds__(256)
void k_frob(const float* __restrict__ m, float* __restrict__ c2) {
  int t = blockIdx.x * 256 + threadIdx.x;
  float4 v = ((const float4*)m)[t];
  float q = v.x * v.x + v.y * v.y + v.z * v.z + v.w * v.w;
#pragma unroll
  for (int o = 32; o > 0; o >>= 1) q += __shfl_down(q, o, 64);
  __shared__ float red[4];
  if ((threadIdx.x & 63) == 0) red[threadIdx.x >> 6] = q;
  __syncthreads();
  if (threadIdx.x == 0) atomicAdd(c2, red[0] + red[1] + red[2] + red[3]);
}

__global__ __launch_bounds__(256)
void k_scale(float* __restrict__ m, const float* __restrict__ scal) {
  float c = sqrtf(scal[0]);        // ||M||_F
  float inv = 1.0f / c;
  int t = blockIdx.x * 256 + threadIdx.x;
  float4 v = ((const float4*)m)[t];
  v.x *= inv; v.y *= inv; v.z *= inv; v.w *= inv;
  ((float4*)m)[t] = v;
}

__global__ __launch_bounds__(256)
void k_setI(float* __restrict__ m) {
  int t = blockIdx.x * 256 + threadIdx.x;
  int idx = t << 2;
  int i = idx >> 11;          // row (D=2048)
  int j0 = idx & (D_DIM - 1);
  float4 v;
  v.x = (j0 + 0 == i) ? 1.f : 0.f;
  v.y = (j0 + 1 == i) ? 1.f : 0.f;
  v.z = (j0 + 2 == i) ? 1.f : 0.f;
  v.w = (j0 + 3 == i) ? 1.f : 0.f;
  ((float4*)m)[t] = v;
}

__global__ __launch_bounds__(256)
void k_trace(const float* __restrict__ m, float* __restrict__ out) {
  __shared__ float red[256];
  float s = 0.f;
  for (int i = threadIdx.x; i < D_DIM; i += 256)
    s += m[(size_t)i * D_DIM + i];
  red[threadIdx.x] = s;
  __syncthreads();
  for (int o = 128; o > 0; o >>= 1) {
    if (threadIdx.x < o) red[threadIdx.x] += red[threadIdx.x + o];
    __syncthreads();
  }
  if (threadIdx.x == 0) out[0] = red[0];
}

// out = trA + trB - 2*sqrt(c)*trace(Y),  c = sqrt(c2)
__global__ __launch_bounds__(256)
void k_final(const float* __restrict__ Y, const float* __restrict__ scal,
             float* __restrict__ out) {
  __shared__ float red[256];
  float s = 0.f;
  for (int i = threadIdx.x; i < D_DIM; i += 256)
    s += Y[(size_t)i * D_DIM + i];
  red[threadIdx.x] = s;
  __syncthreads();
  for (int o = 128; o > 0; o >>= 1) {
    if (threadIdx.x < o) red[threadIdx.x] += red[threadIdx.x + o];
    __syncthreads();
  }
  if (threadIdx.x == 0) {
    float sqrtc = sqrtf(sqrtf(scal[0]));  // c2^(1/4) = sqrt(||M||_F)
    out[0] = scal[1] + scal[2] - 2.0f * sqrtc * red[0];
  }
}

// ---------------- launch ----------------

extern "C" void kernel_launch(void* const* d_in, const int* in_sizes, int n_in,
                              void* d_out, int out_size, void* d_ws,
                              size_t ws_size, hipStream_t stream) {
  (void)in_sizes; (void)n_in; (void)out_size; (void)ws_size;
  const float* za = (const float*)d_in[0];
  const float* zb = (const float*)d_in[1];
  float* out = (float*)d_out;
  float* ws = (float*)d_ws;

  const size_t DD = (size_t)D_DIM * D_DIM;
  float* stat = ws;                 // [0,D)=mean_a [D,2D)=rstd_a [2D,3D)=mean_b [3D,4D)=rstd_b
  float* scal = ws + 4 * D_DIM;     // [0]=c2  [1]=trA  [2]=trB
  float* P0 = ws + 16384;           // 64 KB offset; 4 x 16 MB matrices
  float* P1 = P0 + DD;
  float* P2 = P1 + DD;
  float* P3 = P2 + DD;

  hipMemsetAsync(ws, 0, (4 * D_DIM + 16) * sizeof(float), stream);

  dim3 blk(256);
  k_colstats<<<dim3(8, 16), blk, 0, stream>>>(za, stat, stat + D_DIM);
  k_colstats<<<dim3(8, 16), blk, 0, stream>>>(zb, stat + 2 * D_DIM, stat + 3 * D_DIM);
  k_finalize_stats<<<16, blk, 0, stream>>>(stat);

  dim3 gg(D_DIM / BN, D_DIM / BM);  // (32, 16)
  k_gram<<<gg, blk, 0, stream>>>(za, stat, stat + D_DIM, P0);                  // A
  k_gram<<<gg, blk, 0, stream>>>(zb, stat + 2 * D_DIM, stat + 3 * D_DIM, P1);  // B

  k_trace<<<1, blk, 0, stream>>>(P0, scal + 1);
  k_trace<<<1, blk, 0, stream>>>(P1, scal + 2);

  k_gemm<0><<<gg, blk, 0, stream>>>(P0, P1, P2);  // M = A*B
  k_frob<<<4096, blk, 0, stream>>>(P2, scal);     // c2 = ||M||_F^2
  k_scale<<<4096, blk, 0, stream>>>(P2, scal);    // Y0 = M/c (in place)
  k_setI<<<4096, blk, 0, stream>>>(P1);           // Z0 = I (B's buffer is free now)

  // Newton-Schulz: T = 3I - Z*Y ; Y <- 0.5*Y*T ; Z <- 0.5*T*Z
  float *Y = P2, *Z = P1, *F1 = P0, *F2 = P3;
  for (int it = 0; it < NS_ITERS; ++it) {
    float* T = F1;
    k_gemm<1><<<gg, blk, 0, stream>>>(Z, Y, T);
    float* Yn = F2;
    k_gemm<2><<<gg, blk, 0, stream>>>(Y, T, Yn);
    float* Zn = Y;  // overwrite old Y
    if (it < NS_ITERS - 1)
      k_gemm<2><<<gg, blk, 0, stream>>>(T, Z, Zn);
    float* oldZ = Z;
    Y = Yn; Z = Zn; F1 = T; F2 = oldZ;
  }

  k_final<<<1, blk, 0, stream>>>(Y, scal, out);
}

// Round 2
// 6294.818 us; speedup vs baseline: 2.0527x; 2.0527x over previous
//
#include <hip/hip_runtime.h>
#include <math.h>

typedef unsigned short u16;
typedef unsigned int u32;

#define D_DIM 2048
#define N_ROWS 4096
#define EPS_DIAG 1e-3f
#define NS_ITERS 18

typedef __attribute__((ext_vector_type(8))) short bf16x8;
typedef __attribute__((ext_vector_type(4))) float f32x4;

__device__ __forceinline__ u16 f2bf(float f) {
  u32 u = __float_as_uint(f);
  u += 0x7fffu + ((u >> 16) & 1u);
  return (u16)(u >> 16);
}
__device__ __forceinline__ float bf2f(u16 h) {
  return __uint_as_float(((u32)h) << 16);
}

#define GLD16(g, l)                                                       \
  __builtin_amdgcn_global_load_lds(                                       \
      (const __attribute__((address_space(1))) void*)(g),                 \
      (__attribute__((address_space(3))) void*)(l), 16, 0, 0)

// ---------------- column statistics (mean / rstd, ddof=1) ----------------

__global__ __launch_bounds__(256)
void k_colstats(const float* __restrict__ z, float* __restrict__ sum_,
                float* __restrict__ ssq_) {
  const int c = blockIdx.x * 256 + threadIdx.x;
  const int r0 = blockIdx.y * (N_ROWS / 16);
  float s = 0.f, q = 0.f;
#pragma unroll 8
  for (int r = 0; r < N_ROWS / 16; ++r) {
    float v = z[(size_t)(r0 + r) * D_DIM + c];
    s += v;
    q += v * v;
  }
  atomicAdd(&sum_[c], s);
  atomicAdd(&ssq_[c], q);
}

__global__ __launch_bounds__(256)
void k_finalize_stats(float* stat) {
  const int t = blockIdx.x * 256 + threadIdx.x;
  const int g = t >> 11;
  const int c = t & (D_DIM - 1);
  float* base = stat + g * 2 * D_DIM;
  float s = base[c];
  float q = base[D_DIM + c];
  float mean = s * (1.0f / N_ROWS);
  float var = (q - (float)N_ROWS * mean * mean) * (1.0f / (N_ROWS - 1));
  var = fmaxf(var, 1e-30f);
  base[c] = mean;
  base[D_DIM + c] = 1.0f / sqrtf(var);
}

// ---------------- Gram: out = zhat^T zhat + eps*I, bf16 h/l out ----------------
// 128x64 tiles; triangle-skip (bj > 2bi+1 mirrored from transpose block)

__global__ __launch_bounds__(256)
void k_gram(const float* __restrict__ z, const float* __restrict__ mean,
            const float* __restrict__ rstd, u16* __restrict__ Oh,
            u16* __restrict__ Ol) {
  const int bj = blockIdx.x, bi = blockIdx.y;
  if (bj > 2 * bi + 1) return;
  __shared__ float U[32][132];
  __shared__ float V[32][68];
  const int tid = threadIdx.x;
  const int I = bi * 128;
  const int J = bj * 64;
  const int tx = tid & 15;
  const int ty = tid >> 4;

  const int uc4 = tid & 31;
  const int ur0 = tid >> 5;
  const int vc4 = tid & 15;
  const int vr0 = tid >> 4;

  const float4 mU = ((const float4*)mean)[(I >> 2) + uc4];
  const float4 rU = ((const float4*)rstd)[(I >> 2) + uc4];
  const float4 mV = ((const float4*)mean)[(J >> 2) + vc4];
  const float4 rV = ((const float4*)rstd)[(J >> 2) + vc4];

  float acc[8][4];
#pragma unroll
  for (int i = 0; i < 8; ++i)
#pragma unroll
    for (int j = 0; j < 4; ++j) acc[i][j] = 0.f;

  for (int k0 = 0; k0 < N_ROWS; k0 += 32) {
#pragma unroll
    for (int p = 0; p < 4; ++p) {
      int rr = ur0 + p * 8;
      float4 v = *(const float4*)(z + (size_t)(k0 + rr) * D_DIM + I + uc4 * 4);
      v.x = (v.x - mU.x) * rU.x;
      v.y = (v.y - mU.y) * rU.y;
      v.z = (v.z - mU.z) * rU.z;
      v.w = (v.w - mU.w) * rU.w;
      *(float4*)&U[rr][uc4 * 4] = v;
    }
#pragma unroll
    for (int p = 0; p < 2; ++p) {
      int rr = vr0 + p * 16;
      float4 v = *(const float4*)(z + (size_t)(k0 + rr) * D_DIM + J + vc4 * 4);
      v.x = (v.x - mV.x) * rV.x;
      v.y = (v.y - mV.y) * rV.y;
      v.z = (v.z - mV.z) * rV.z;
      v.w = (v.w - mV.w) * rV.w;
      *(float4*)&V[rr][vc4 * 4] = v;
    }
    __syncthreads();
#pragma unroll
    for (int kk = 0; kk < 32; ++kk) {
      float4 a0 = *(const float4*)&U[kk][ty * 4];
      float4 a1 = *(const float4*)&U[kk][64 + ty * 4];
      float4 b0 = *(const float4*)&V[kk][tx * 4];
      float av[8] = {a0.x, a0.y, a0.z, a0.w, a1.x, a1.y, a1.z, a1.w};
      float bv[4] = {b0.x, b0.y, b0.z, b0.w};
#pragma unroll
      for (int i = 0; i < 8; ++i)
#pragma unroll
        for (int j = 0; j < 4; ++j) acc[i][j] += av[i] * bv[j];
    }
    __syncthreads();
  }

#pragma unroll
  for (int i = 0; i < 8; ++i) {
    int row = (i < 4) ? (ty * 4 + i) : (64 + ty * 4 + (i - 4));
    int gi = I + row;
#pragma unroll
    for (int j = 0; j < 4; ++j) {
      int gj = J + tx * 4 + j;
      float val = acc[i][j] + ((gi == gj) ? EPS_DIAG : 0.f);
      u16 h = f2bf(val);
      u16 l = f2bf(val - bf2f(h));
      Oh[(size_t)gi * D_DIM + gj] = h;
      Ol[(size_t)gi * D_DIM + gj] = l;
      if (gi > gj) {
        Oh[(size_t)gj * D_DIM + gi] = h;
        Ol[(size_t)gj * D_DIM + gi] = l;
      }
    }
  }
}

// ---------------- split-bf16 MFMA GEMM: C = op(P*Q), 2048^3 ----------------
// P,Q,C all row-major bf16 (h,l) pairs. 128x128 tile, 4 waves of 64x64.
// MODE 0: C = P*Q   1: C = 3I - P*Q   2: C = 0.5*P*Q   3: C = (0.5/sqrt(scal0))*P*Q

#define AH 0
#define AL 4096
#define BH 8192
#define BL 12288

template <int MODE>
__global__ __launch_bounds__(256)
void k_mm(const u16* __restrict__ Ph, const u16* __restrict__ Pl,
          const u16* __restrict__ Qh, const u16* __restrict__ Ql,
          u16* __restrict__ Ch, u16* __restrict__ Cl,
          const float* __restrict__ scal) {
  __shared__ u16 lds[16384];
  const int tid = threadIdx.x;
  const int lane = tid & 63;
  const int w = tid >> 6;
  const int I = blockIdx.y * 128;
  const int J = blockIdx.x * 128;
  const int wm = w >> 1, wn = w & 1;

  const int kp = tid >> 4;  // 0..15 (k-pair)
  const int nc = tid & 15;  // 0..15 (8-col chunk)
  const int n0 = nc * 8;

  f32x4 acc[4][4];
#pragma unroll
  for (int i = 0; i < 4; ++i)
#pragma unroll
    for (int j = 0; j < 4; ++j) acc[i][j] = (f32x4){0.f, 0.f, 0.f, 0.f};

  for (int k0 = 0; k0 < D_DIM; k0 += 32) {
    // ---- A-operand: fragment-ordered global_load_lds (16B/lane) ----
#pragma unroll
    for (int p = 0; p < 2; ++p) {
      int s = p * 256 + w * 64 + lane;
      int t = s >> 6, qq = (s >> 4) & 3, m = s & 15;
      size_t go = (size_t)(I + t * 16 + m) * D_DIM + (k0 + qq * 8);
      int base = (p * 256 + w * 64) * 8;
      GLD16(Ph + go, &lds[AH + base]);
      GLD16(Pl + go, &lds[AL + base]);
    }
    // ---- B-operand: load 2 k-rows, pack k-pairs, transposed ds_write_b32 ----
    {
      size_t ro = (size_t)(k0 + 2 * kp) * D_DIM + J + n0;
      union U4 { uint4 v; u16 s[8]; };
      U4 h0, h1, l0, l1;
      h0.v = *(const uint4*)(Qh + ro);
      h1.v = *(const uint4*)(Qh + ro + D_DIM);
      l0.v = *(const uint4*)(Ql + ro);
      l1.v = *(const uint4*)(Ql + ro + D_DIM);
      const int qq = kp >> 2;
      const int kd = (kp & 3) * 2;
#pragma unroll
      for (int j = 0; j < 8; ++j) {
        int n = n0 + j;
        int u = n >> 4, nl = n & 15;
        int slot = (u * 64 + qq * 16 + nl) ^ u;  // XOR-swizzle (bank spread)
        *(u32*)&lds[BH + slot * 8 + kd] = (u32)h0.s[j] | ((u32)h1.s[j] << 16);
        *(u32*)&lds[BL + slot * 8 + kd] = (u32)l0.s[j] | ((u32)l1.s[j] << 16);
      }
    }
    __syncthreads();
    // ---- fragments + 48 MFMAs ----
    bf16x8 ah[4], al[4], bh[4], bl[4];
#pragma unroll
    for (int i = 0; i < 4; ++i) {
      int t = wm * 4 + i;
      ah[i] = *(const bf16x8*)&lds[AH + (t * 64 + lane) * 8];
      al[i] = *(const bf16x8*)&lds[AL + (t * 64 + lane) * 8];
    }
#pragma unroll
    for (int j = 0; j < 4; ++j) {
      int u = wn * 4 + j;
      int sl = (u * 64 + lane) ^ u;
      bh[j] = *(const bf16x8*)&lds[BH + sl * 8];
      bl[j] = *(const bf16x8*)&lds[BL + sl * 8];
    }
#pragma unroll
    for (int i = 0; i < 4; ++i)
#pragma unroll
      for (int j = 0; j < 4; ++j) {
        acc[i][j] = __builtin_amdgcn_mfma_f32_16x16x32_bf16(ah[i], bh[j],
                                                            acc[i][j], 0, 0, 0);
        acc[i][j] = __builtin_amdgcn_mfma_f32_16x16x32_bf16(ah[i], bl[j],
                                                            acc[i][j], 0, 0, 0);
        acc[i][j] = __builtin_amdgcn_mfma_f32_16x16x32_bf16(al[i], bh[j],
                                                            acc[i][j], 0, 0, 0);
      }
    __syncthreads();
  }

  // ---- epilogue: mode transform + split to bf16 h/l ----
  float mul = (MODE == 2) ? 0.5f : 1.0f;
  if (MODE == 3) mul = 0.5f / sqrtf(scal[0]);
  const int qd = lane >> 4;
  const int nl = lane & 15;
#pragma unroll
  for (int i = 0; i < 4; ++i)
#pragma unroll
    for (int j = 0; j < 4; ++j)
#pragma unroll
      for (int r = 0; r < 4; ++r) {
        int gi = I + wm * 64 + i * 16 + qd * 4 + r;
        int gj = J + wn * 64 + j * 16 + nl;
        float v = acc[i][j][r];
        if (MODE == 1)
          v = ((gi == gj) ? 3.0f : 0.0f) - v;
        else
          v *= mul;
        u16 h = f2bf(v);
        u16 l = f2bf(v - bf2f(h));
        Ch[(size_t)gi * D_DIM + gj] = h;
        Cl[(size_t)gi * D_DIM + gj] = l;
      }
}

// ---------------- small utility kernels ----------------

__global__ __launch_bounds__(256)
void k_frob_hl(const u16* __restrict__ mh, const u16* __restrict__ ml,
               float* __restrict__ c2) {
  size_t t = (size_t)blockIdx.x * 256 + threadIdx.x;
  uint2 hv = ((const uint2*)mh)[t];
  uint2 lv = ((const uint2*)ml)[t];
  float v0 = bf2f((u16)(hv.x & 0xffff)) + bf2f((u16)(lv.x & 0xffff));
  float v1 = bf2f((u16)(hv.x >> 16)) + bf2f((u16)(lv.x >> 16));
  float v2 = bf2f((u16)(hv.y & 0xffff)) + bf2f((u16)(lv.y & 0xffff));
  float v3 = bf2f((u16)(hv.y >> 16)) + bf2f((u16)(lv.y >> 16));
  float q = v0 * v0 + v1 * v1 + v2 * v2 + v3 * v3;
#pragma unroll
  for (int o = 32; o > 0; o >>= 1) q += __shfl_down(q, o, 64);
  __shared__ float red[4];
  if ((threadIdx.x & 63) == 0) red[threadIdx.x >> 6] = q;
  __syncthreads();
  if (threadIdx.x == 0) atomicAdd(c2, red[0] + red[1] + red[2] + red[3]);
}

// T1 = 3I - M/c, Z1 = 0.5*T1 (elementwise; folds away first NS GEMM)
__global__ __launch_bounds__(256)
void k_t1z1(const u16* __restrict__ Mh, const u16* __restrict__ Ml,
            const float* __restrict__ scal, u16* __restrict__ Th,
            u16* __restrict__ Tl, u16* __restrict__ Zh, u16* __restrict__ Zl) {
  size_t t = (size_t)blockIdx.x * 256 + threadIdx.x;
  float invc = 1.0f / sqrtf(scal[0]);
  size_t e = t * 4;
  int i = (int)(e >> 11);
  int j0 = (int)(e & (D_DIM - 1));
  uint2 hv = ((const uint2*)Mh)[t];
  uint2 lv = ((const uint2*)Ml)[t];
  u16 hs[4] = {(u16)(hv.x & 0xffff), (u16)(hv.x >> 16), (u16)(hv.y & 0xffff),
               (u16)(hv.y >> 16)};
  u16 ls[4] = {(u16)(lv.x & 0xffff), (u16)(lv.x >> 16), (u16)(lv.y & 0xffff),
               (u16)(lv.y >> 16)};
  u16 th[4], tl[4], zh[4], zl[4];
#pragma unroll
  for (int c = 0; c < 4; ++c) {
    float m = bf2f(hs[c]) + bf2f(ls[c]);
    float tv = ((i == j0 + c) ? 3.0f : 0.0f) - m * invc;
    th[c] = f2bf(tv);
    tl[c] = f2bf(tv - bf2f(th[c]));
    float zv = 0.5f * tv;
    zh[c] = f2bf(zv);
    zl[c] = f2bf(zv - bf2f(zh[c]));
  }
  ((uint2*)Th)[t] = make_uint2((u32)th[0] | ((u32)th[1] << 16),
                               (u32)th[2] | ((u32)th[3] << 16));
  ((uint2*)Tl)[t] = make_uint2((u32)tl[0] | ((u32)tl[1] << 16),
                               (u32)tl[2] | ((u32)tl[3] << 16));
  ((uint2*)Zh)[t] = make_uint2((u32)zh[0] | ((u32)zh[1] << 16),
                               (u32)zh[2] | ((u32)zh[3] << 16));
  ((uint2*)Zl)[t] = make_uint2((u32)zl[0] | ((u32)zl[1] << 16),
                               (u32)zl[2] | ((u32)zl[3] << 16));
}

__global__ __launch_bounds__(256)
void k_trace_hl(const u16* __restrict__ mh, const u16* __restrict__ ml,
                float* __restrict__ out) {
  __shared__ float red[256];
  float s = 0.f;
  for (int i = threadIdx.x; i < D_DIM; i += 256) {
    size_t d = (size_t)i * (D_DIM + 1);
    s += bf2f(mh[d]) + bf2f(ml[d]);
  }
  red[threadIdx.x] = s;
  __syncthreads();
  for (int o = 128; o > 0; o >>= 1) {
    if (threadIdx.x < o) red[threadIdx.x] += red[threadIdx.x + o];
    __syncthreads();
  }
  if (threadIdx.x == 0) out[0] = red[0];
}

// out = trA + trB - 2*sqrt(c)*trace(Y),  c = sqrt(c2)
__global__ __launch_bounds__(256)
void k_final(const u16* __restrict__ Yh, const u16* __restrict__ Yl,
             const float* __restrict__ scal, float* __restrict__ out) {
  __shared__ float red[256];
  float s = 0.f;
  for (int i = threadIdx.x; i < D_DIM; i += 256) {
    size_t d = (size_t)i * (D_DIM + 1);
    s += bf2f(Yh[d]) + bf2f(Yl[d]);
  }
  red[threadIdx.x] = s;
  __syncthreads();
  for (int o = 128; o > 0; o >>= 1) {
    if (threadIdx.x < o) red[threadIdx.x] += red[threadIdx.x + o];
    __syncthreads();
  }
  if (threadIdx.x == 0) {
    float sqrtc = sqrtf(sqrtf(scal[0]));  // c2^(1/4) = sqrt(||M||_F)
    out[0] = scal[1] + scal[2] - 2.0f * sqrtc * red[0];
  }
}

// ---------------- launch ----------------

extern "C" void kernel_launch(void* const* d_in, const int* in_sizes, int n_in,
                              void* d_out, int out_size, void* d_ws,
                              size_t ws_size, hipStream_t stream) {
  (void)in_sizes; (void)n_in; (void)out_size; (void)ws_size;
  const float* za = (const float*)d_in[0];
  const float* zb = (const float*)d_in[1];
  float* out = (float*)d_out;
  float* ws = (float*)d_ws;

  float* stat = ws;              // means/rstds
  float* scal = ws + 4 * D_DIM;  // [0]=c2 [1]=trA [2]=trB
  u16* b[8];
  {
    char* pool = (char*)d_ws + 65536;
    for (int i = 0; i < 8; ++i) b[i] = (u16*)(pool + (size_t)i * 8388608);
  }
#define PH(p) b[2 * (p)]
#define PL(p) b[2 * (p) + 1]

  hipMemsetAsync(ws, 0, (4 * D_DIM + 16) * sizeof(float), stream);

  dim3 blk(256);
  k_colstats<<<dim3(8, 16), blk, 0, stream>>>(za, stat, stat + D_DIM);
  k_colstats<<<dim3(8, 16), blk, 0, stream>>>(zb, stat + 2 * D_DIM,
                                              stat + 3 * D_DIM);
  k_finalize_stats<<<16, blk, 0, stream>>>(stat);

  dim3 gg(32, 16);
  k_gram<<<gg, blk, 0, stream>>>(za, stat, stat + D_DIM, PH(0), PL(0));  // A
  k_gram<<<gg, blk, 0, stream>>>(zb, stat + 2 * D_DIM, stat + 3 * D_DIM,
                                 PH(1), PL(1));                          // B
  k_trace_hl<<<1, blk, 0, stream>>>(PH(0), PL(0), scal + 1);
  k_trace_hl<<<1, blk, 0, stream>>>(PH(1), PL(1), scal + 2);

  dim3 gm(16, 16);
  // M = A*B  -> pair 2
  k_mm<0><<<gm, blk, 0, stream>>>(PH(0), PL(0), PH(1), PL(1), PH(2), PL(2),
                                  scal);
  k_frob_hl<<<4096, blk, 0, stream>>>(PH(2), PL(2), scal);
  // T1 -> pair 0, Z1 -> pair 1 (A,B dead)
  k_t1z1<<<4096, blk, 0, stream>>>(PH(2), PL(2), scal, PH(0), PL(0), PH(1),
                                   PL(1));
  // Y1 = (0.5/c) * M * T1 -> pair 3
  k_mm<3><<<gm, blk, 0, stream>>>(PH(2), PL(2), PH(0), PL(0), PH(3), PL(3),
                                  scal);

  // state: Y=pair3, Z=pair1, free fA=pair0, fB=pair2
  int Y = 3, Z = 1, fA = 0, fB = 2;
  for (int it = 2; it <= NS_ITERS; ++it) {
    // T = 3I - Z*Y -> fA
    k_mm<1><<<gm, blk, 0, stream>>>(PH(Z), PL(Z), PH(Y), PL(Y), PH(fA), PL(fA),
                                    scal);
    // Yn = 0.5*Y*T -> fB
    k_mm<2><<<gm, blk, 0, stream>>>(PH(Y), PL(Y), PH(fA), PL(fA), PH(fB),
                                    PL(fB), scal);
    // Zn = 0.5*T*Z -> old Y
    if (it < NS_ITERS)
      k_mm<2><<<gm, blk, 0, stream>>>(PH(fA), PL(fA), PH(Z), PL(Z), PH(Y),
                                      PL(Y), scal);
    int oy = Y, oz = Z, oa = fA, ob = fB;
    Y = ob;
    Z = oy;
    fA = oz;
    fB = oa;
  }

  k_final<<<1, blk, 0, stream>>>(PH(Y), PL(Y), scal, out);
#undef PH
#undef PL
}

// Round 4
// 4104.811 us; speedup vs baseline: 3.1479x; 1.5335x over previous
//
#include <hip/hip_runtime.h>
#include <math.h>

typedef unsigned short u16;
typedef unsigned int u32;

#define D_DIM 2048
#define N_ROWS 4096
#define EPS_DIAG 1e-3f
#define NS_ITERS 16

typedef __attribute__((ext_vector_type(8))) short bf16x8;
typedef __attribute__((ext_vector_type(4))) float f32x4;

__device__ __forceinline__ u16 f2bf(float f) {
  u32 u = __float_as_uint(f);
  u += 0x7fffu + ((u >> 16) & 1u);
  return (u16)(u >> 16);
}
__device__ __forceinline__ float bf2f(u16 h) {
  return __uint_as_float(((u32)h) << 16);
}

#define GLD16(g, l)                                        \
  __builtin_amdgcn_global_load_lds(                        \
      (const __attribute__((address_space(1))) void*)(g),  \
      (__attribute__((address_space(3))) void*)(l), 16, 0, 0)

// ---------------- column statistics (mean / rstd, ddof=1) ----------------

__global__ __launch_bounds__(256)
void k_colstats(const float* __restrict__ z, float* __restrict__ sum_,
                float* __restrict__ ssq_) {
  const int c = blockIdx.x * 256 + threadIdx.x;
  const int r0 = blockIdx.y * (N_ROWS / 16);
  float s = 0.f, q = 0.f;
#pragma unroll 8
  for (int r = 0; r < N_ROWS / 16; ++r) {
    float v = z[(size_t)(r0 + r) * D_DIM + c];
    s += v;
    q += v * v;
  }
  atomicAdd(&sum_[c], s);
  atomicAdd(&ssq_[c], q);
}

__global__ __launch_bounds__(256)
void k_finalize_stats(float* stat) {
  const int t = blockIdx.x * 256 + threadIdx.x;
  const int g = t >> 11;
  const int c = t & (D_DIM - 1);
  float* base = stat + g * 2 * D_DIM;
  float s = base[c];
  float q = base[D_DIM + c];
  float mean = s * (1.0f / N_ROWS);
  float var = (q - (float)N_ROWS * mean * mean) * (1.0f / (N_ROWS - 1));
  var = fmaxf(var, 1e-30f);
  base[c] = mean;
  base[D_DIM + c] = 1.0f / sqrtf(var);
}

// ---------------- standardize + split z into bf16 h/l ----------------
// zh/zl are each N_ROWS*D_DIM u16 = 16 MB (span TWO 8MB pool slots!)

__global__ __launch_bounds__(256)
void k_zsplit(const float* __restrict__ z, const float* __restrict__ mean,
              const float* __restrict__ rstd, u16* __restrict__ zh,
              u16* __restrict__ zl) {
  size_t t = (size_t)blockIdx.x * 256 + threadIdx.x;
  int ci = (int)(t & 511);  // float4 column index
  float4 v = ((const float4*)z)[t];
  float4 m = ((const float4*)mean)[ci];
  float4 r = ((const float4*)rstd)[ci];
  float x[4] = {(v.x - m.x) * r.x, (v.y - m.y) * r.y, (v.z - m.z) * r.z,
                (v.w - m.w) * r.w};
  u16 h[4], l[4];
#pragma unroll
  for (int i = 0; i < 4; ++i) {
    h[i] = f2bf(x[i]);
    l[i] = f2bf(x[i] - bf2f(h[i]));
  }
  ((uint2*)zh)[t] = make_uint2((u32)h[0] | ((u32)h[1] << 16),
                               (u32)h[2] | ((u32)h[3] << 16));
  ((uint2*)zl)[t] = make_uint2((u32)l[0] | ((u32)l[1] << 16),
                               (u32)l[2] | ((u32)l[3] << 16));
}

// ---------------- MFMA Gram: C = zhat^T zhat + eps*I ----------------
// Tile 128(M) x 64(N), K = N_ROWS, both operands transpose-packed from
// row-major zh/zl. Double-buffered LDS, 1 barrier/iter.
// LDS per buffer (u16 idx): AH=0 AL=4096 BH=8192 BL=10240, stride 12288.

__global__ __launch_bounds__(256)
void k_gram_mm(const u16* __restrict__ zh, const u16* __restrict__ zl,
               u16* __restrict__ Oh, u16* __restrict__ Ol) {
  __shared__ u16 lds[24576];
  const int tid = threadIdx.x;
  const int lane = tid & 63;
  const int w = tid >> 6;
  const int I = blockIdx.y * 128;
  const int J = blockIdx.x * 64;
  const int kp = tid >> 4;  // 0..15 k-pair
  const int nc = tid & 15;
  const int qq = kp >> 2;
  const int kd = (kp & 3) * 2;

  const size_t aro = (size_t)(2 * kp) * D_DIM + I + nc * 8;  // A: 8 cols
  const size_t bro = (size_t)(2 * kp) * D_DIM + J + nc * 4;  // B: 4 cols

  union U4 { uint4 v; u16 s[8]; };
  union U2 { uint2 v; u16 s[4]; };
  U4 ah0, ah1, al0, al1;
  U2 bh0, bh1, bl0, bl1;

  f32x4 acc[2][4];
#pragma unroll
  for (int i = 0; i < 2; ++i)
#pragma unroll
    for (int j = 0; j < 4; ++j) acc[i][j] = (f32x4){0.f, 0.f, 0.f, 0.f};

#define GRAM_LOAD(k1)                                   \
  {                                                     \
    size_t ao = aro + (size_t)(k1)*D_DIM;               \
    size_t bo = bro + (size_t)(k1)*D_DIM;               \
    ah0.v = *(const uint4*)(zh + ao);                   \
    ah1.v = *(const uint4*)(zh + ao + D_DIM);           \
    al0.v = *(const uint4*)(zl + ao);                   \
    al1.v = *(const uint4*)(zl + ao + D_DIM);           \
    bh0.v = *(const uint2*)(zh + bo);                   \
    bh1.v = *(const uint2*)(zh + bo + D_DIM);           \
    bl0.v = *(const uint2*)(zl + bo);                   \
    bl1.v = *(const uint2*)(zl + bo + D_DIM);           \
  }

#define GRAM_PACK(buf)                                                      \
  {                                                                         \
    _Pragma("unroll") for (int j = 0; j < 8; ++j) {                         \
      int mc = nc * 8 + j;                                                  \
      int t = mc >> 4, ml = mc & 15;                                        \
      int slot = (t * 64 + qq * 16 + ml) ^ t;                               \
      *(u32*)&lds[(buf) + slot * 8 + kd] =                                  \
          (u32)ah0.s[j] | ((u32)ah1.s[j] << 16);                            \
      *(u32*)&lds[(buf) + 4096 + slot * 8 + kd] =                           \
          (u32)al0.s[j] | ((u32)al1.s[j] << 16);                            \
    }                                                                       \
    _Pragma("unroll") for (int j = 0; j < 4; ++j) {                         \
      int n = nc * 4 + j;                                                   \
      int u = n >> 4, nl = n & 15;                                          \
      int slot = (u * 64 + qq * 16 + nl) ^ u;                               \
      *(u32*)&lds[(buf) + 8192 + slot * 8 + kd] =                           \
          (u32)bh0.s[j] | ((u32)bh1.s[j] << 16);                            \
      *(u32*)&lds[(buf) + 10240 + slot * 8 + kd] =                          \
          (u32)bl0.s[j] | ((u32)bl1.s[j] << 16);                            \
    }                                                                       \
  }

  GRAM_LOAD(0);
  GRAM_PACK(0);
  __syncthreads();

  for (int k = 0; k < N_ROWS / 32; ++k) {
    const int cur = (k & 1) * 12288;
    const int nxt = 12288 - cur;
    if (k < N_ROWS / 32 - 1) GRAM_LOAD((k + 1) * 32);

    bf16x8 fah[2], fal[2], fbh[4], fbl[4];
#pragma unroll
    for (int i = 0; i < 2; ++i) {
      int t = w * 2 + i;
      int sl = (t * 64 + lane) ^ t;
      fah[i] = *(const bf16x8*)&lds[cur + sl * 8];
      fal[i] = *(const bf16x8*)&lds[cur + 4096 + sl * 8];
    }
#pragma unroll
    for (int j = 0; j < 4; ++j) {
      int sl = (j * 64 + lane) ^ j;
      fbh[j] = *(const bf16x8*)&lds[cur + 8192 + sl * 8];
      fbl[j] = *(const bf16x8*)&lds[cur + 10240 + sl * 8];
    }
#pragma unroll
    for (int i = 0; i < 2; ++i)
#pragma unroll
      for (int j = 0; j < 4; ++j) {
        acc[i][j] = __builtin_amdgcn_mfma_f32_16x16x32_bf16(fah[i], fbh[j],
                                                            acc[i][j], 0, 0, 0);
        acc[i][j] = __builtin_amdgcn_mfma_f32_16x16x32_bf16(fah[i], fbl[j],
                                                            acc[i][j], 0, 0, 0);
        acc[i][j] = __builtin_amdgcn_mfma_f32_16x16x32_bf16(fal[i], fbh[j],
                                                            acc[i][j], 0, 0, 0);
      }
    if (k < N_ROWS / 32 - 1) GRAM_PACK(nxt);
    __syncthreads();
  }

  const int qd = lane >> 4;
  const int nl = lane & 15;
#pragma unroll
  for (int i = 0; i < 2; ++i)
#pragma unroll
    for (int j = 0; j < 4; ++j)
#pragma unroll
      for (int r = 0; r < 4; ++r) {
        int gi = I + w * 32 + i * 16 + qd * 4 + r;
        int gj = J + j * 16 + nl;
        float v = acc[i][j][r] + ((gi == gj) ? EPS_DIAG : 0.f);
        u16 h = f2bf(v);
        u16 l = f2bf(v - bf2f(h));
        Oh[(size_t)gi * D_DIM + gj] = h;
        Ol[(size_t)gi * D_DIM + gj] = l;
      }
#undef GRAM_LOAD
#undef GRAM_PACK
}

// ---------------- split-bf16 MFMA GEMM: C = op(P*Q), 2048^3 ----------------
// Tile 128x64, 512 blocks, double-buffered LDS, pipelined prefetch.
// MODE 0: C=P*Q  1: C=3I-P*Q  2: C=0.5*P*Q  3: C=(0.5/sqrt(scal0))*P*Q

template <int MODE>
__global__ __launch_bounds__(256)
void k_mm(const u16* __restrict__ Ph, const u16* __restrict__ Pl,
          const u16* __restrict__ Qh, const u16* __restrict__ Ql,
          u16* __restrict__ Ch, u16* __restrict__ Cl,
          const float* __restrict__ scal) {
  __shared__ u16 lds[24576];
  const int tid = threadIdx.x;
  const int lane = tid & 63;
  const int w = tid >> 6;
  const int I = blockIdx.y * 128;
  const int J = blockIdx.x * 64;
  const int kp = tid >> 4;
  const int nc = tid & 15;
  const int qq = kp >> 2;
  const int kd = (kp & 3) * 2;

  // A staging via global_load_lds, fragment-ordered. LDS base is
  // WAVE-UNIFORM (round-2-proven form); lane data lands at base+lane*16B.
  size_t aro[2];
  int acl[2], abase[2];
#pragma unroll
  for (int p = 0; p < 2; ++p) {
    int s = p * 256 + w * 64 + lane;
    aro[p] = (size_t)(I + (s >> 6) * 16 + (s & 15)) * D_DIM;
    acl[p] = ((s >> 4) & 3) * 8;
    abase[p] = (p * 256 + w * 64) * 8;
  }
  const size_t bro = (size_t)(2 * kp) * D_DIM + J + nc * 4;

  union U2 { uint2 v; u16 s[4]; };
  U2 bh0, bh1, bl0, bl1;

  f32x4 acc[2][4];
#pragma unroll
  for (int i = 0; i < 2; ++i)
#pragma unroll
    for (int j = 0; j < 4; ++j) acc[i][j] = (f32x4){0.f, 0.f, 0.f, 0.f};

#define MM_STAGE_A(k1, buf)                                               \
  {                                                                       \
    _Pragma("unroll") for (int p = 0; p < 2; ++p) {                       \
      GLD16(Ph + aro[p] + (k1) + acl[p], &lds[(buf) + abase[p]]);         \
      GLD16(Pl + aro[p] + (k1) + acl[p], &lds[(buf) + 4096 + abase[p]]);  \
    }                                                                     \
  }
#define MM_LOAD_B(k1)                              \
  {                                                \
    size_t bo = bro + (size_t)(k1)*D_DIM;          \
    bh0.v = *(const uint2*)(Qh + bo);              \
    bh1.v = *(const uint2*)(Qh + bo + D_DIM);      \
    bl0.v = *(const uint2*)(Ql + bo);              \
    bl1.v = *(const uint2*)(Ql + bo + D_DIM);      \
  }
#define MM_PACK_B(buf)                                                      \
  {                                                                         \
    _Pragma("unroll") for (int j = 0; j < 4; ++j) {                         \
      int n = nc * 4 + j;                                                   \
      int u = n >> 4, nl2 = n & 15;                                         \
      int slot = (u * 64 + qq * 16 + nl2) ^ u;                              \
      *(u32*)&lds[(buf) + 8192 + slot * 8 + kd] =                           \
          (u32)bh0.s[j] | ((u32)bh1.s[j] << 16);                            \
      *(u32*)&lds[(buf) + 10240 + slot * 8 + kd] =                          \
          (u32)bl0.s[j] | ((u32)bl1.s[j] << 16);                            \
    }                                                                       \
  }

  MM_STAGE_A(0, 0);
  MM_LOAD_B(0);
  MM_PACK_B(0);
  __syncthreads();

  for (int k = 0; k < D_DIM / 32; ++k) {
    const int cur = (k & 1) * 12288;
    const int nxt = 12288 - cur;
    if (k < D_DIM / 32 - 1) {
      MM_STAGE_A((k + 1) * 32, nxt);
      MM_LOAD_B((k + 1) * 32);
    }
    bf16x8 fah[2], fal[2], fbh[4], fbl[4];
#pragma unroll
    for (int i = 0; i < 2; ++i) {
      int t = w * 2 + i;
      fah[i] = *(const bf16x8*)&lds[cur + (t * 64 + lane) * 8];
      fal[i] = *(const bf16x8*)&lds[cur + 4096 + (t * 64 + lane) * 8];
    }
#pragma unroll
    for (int j = 0; j < 4; ++j) {
      int sl = (j * 64 + lane) ^ j;
      fbh[j] = *(const bf16x8*)&lds[cur + 8192 + sl * 8];
      fbl[j] = *(const bf16x8*)&lds[cur + 10240 + sl * 8];
    }
#pragma unroll
    for (int i = 0; i < 2; ++i)
#pragma unroll
      for (int j = 0; j < 4; ++j) {
        acc[i][j] = __builtin_amdgcn_mfma_f32_16x16x32_bf16(fah[i], fbh[j],
                                                            acc[i][j], 0, 0, 0);
        acc[i][j] = __builtin_amdgcn_mfma_f32_16x16x32_bf16(fah[i], fbl[j],
                                                            acc[i][j], 0, 0, 0);
        acc[i][j] = __builtin_amdgcn_mfma_f32_16x16x32_bf16(fal[i], fbh[j],
                                                            acc[i][j], 0, 0, 0);
      }
    if (k < D_DIM / 32 - 1) MM_PACK_B(nxt);
    __syncthreads();
  }

  float mul = (MODE == 2) ? 0.5f : 1.0f;
  if (MODE == 3) mul = 0.5f / sqrtf(scal[0]);
  const int qd = lane >> 4;
  const int nl = lane & 15;
#pragma unroll
  for (int i = 0; i < 2; ++i)
#pragma unroll
    for (int j = 0; j < 4; ++j)
#pragma unroll
      for (int r = 0; r < 4; ++r) {
        int gi = I + w * 32 + i * 16 + qd * 4 + r;
        int gj = J + j * 16 + nl;
        float v = acc[i][j][r];
        if (MODE == 1)
          v = ((gi == gj) ? 3.0f : 0.0f) - v;
        else
          v *= mul;
        u16 h = f2bf(v);
        u16 l = f2bf(v - bf2f(h));
        Ch[(size_t)gi * D_DIM + gj] = h;
        Cl[(size_t)gi * D_DIM + gj] = l;
      }
#undef MM_STAGE_A
#undef MM_LOAD_B
#undef MM_PACK_B
}

// ---------------- small utility kernels ----------------

__global__ __launch_bounds__(256)
void k_frob_hl(const u16* __restrict__ mh, const u16* __restrict__ ml,
               float* __restrict__ c2) {
  size_t t = (size_t)blockIdx.x * 256 + threadIdx.x;
  uint2 hv = ((const uint2*)mh)[t];
  uint2 lv = ((const uint2*)ml)[t];
  float v0 = bf2f((u16)(hv.x & 0xffff)) + bf2f((u16)(lv.x & 0xffff));
  float v1 = bf2f((u16)(hv.x >> 16)) + bf2f((u16)(lv.x >> 16));
  float v2 = bf2f((u16)(hv.y & 0xffff)) + bf2f((u16)(lv.y & 0xffff));
  float v3 = bf2f((u16)(hv.y >> 16)) + bf2f((u16)(lv.y >> 16));
  float q = v0 * v0 + v1 * v1 + v2 * v2 + v3 * v3;
#pragma unroll
  for (int o = 32; o > 0; o >>= 1) q += __shfl_down(q, o, 64);
  __shared__ float red[4];
  if ((threadIdx.x & 63) == 0) red[threadIdx.x >> 6] = q;
  __syncthreads();
  if (threadIdx.x == 0) atomicAdd(c2, red[0] + red[1] + red[2] + red[3]);
}

// T1 = 3I - M/c, Z1 = 0.5*T1
__global__ __launch_bounds__(256)
void k_t1z1(const u16* __restrict__ Mh, const u16* __restrict__ Ml,
            const float* __restrict__ scal, u16* __restrict__ Th,
            u16* __restrict__ Tl, u16* __restrict__ Zh, u16* __restrict__ Zl) {
  size_t t = (size_t)blockIdx.x * 256 + threadIdx.x;
  float invc = 1.0f / sqrtf(scal[0]);
  size_t e = t * 4;
  int i = (int)(e >> 11);
  int j0 = (int)(e & (D_DIM - 1));
  uint2 hv = ((const uint2*)Mh)[t];
  uint2 lv = ((const uint2*)Ml)[t];
  u16 hs[4] = {(u16)(hv.x & 0xffff), (u16)(hv.x >> 16), (u16)(hv.y & 0xffff),
               (u16)(hv.y >> 16)};
  u16 ls[4] = {(u16)(lv.x & 0xffff), (u16)(lv.x >> 16), (u16)(lv.y & 0xffff),
               (u16)(lv.y >> 16)};
  u16 th[4], tl[4], zh[4], zl[4];
#pragma unroll
  for (int c = 0; c < 4; ++c) {
    float m = bf2f(hs[c]) + bf2f(ls[c]);
    float tv = ((i == j0 + c) ? 3.0f : 0.0f) - m * invc;
    th[c] = f2bf(tv);
    tl[c] = f2bf(tv - bf2f(th[c]));
    float zv = 0.5f * tv;
    zh[c] = f2bf(zv);
    zl[c] = f2bf(zv - bf2f(zh[c]));
  }
  ((uint2*)Th)[t] = make_uint2((u32)th[0] | ((u32)th[1] << 16),
                               (u32)th[2] | ((u32)th[3] << 16));
  ((uint2*)Tl)[t] = make_uint2((u32)tl[0] | ((u32)tl[1] << 16),
                               (u32)tl[2] | ((u32)tl[3] << 16));
  ((uint2*)Zh)[t] = make_uint2((u32)zh[0] | ((u32)zh[1] << 16),
                               (u32)zh[2] | ((u32)zh[3] << 16));
  ((uint2*)Zl)[t] = make_uint2((u32)zl[0] | ((u32)zl[1] << 16),
                               (u32)zl[2] | ((u32)zl[3] << 16));
}

__global__ __launch_bounds__(256)
void k_trace_hl(const u16* __restrict__ mh, const u16* __restrict__ ml,
                float* __restrict__ out) {
  __shared__ float red[256];
  float s = 0.f;
  for (int i = threadIdx.x; i < D_DIM; i += 256) {
    size_t d = (size_t)i * (D_DIM + 1);
    s += bf2f(mh[d]) + bf2f(ml[d]);
  }
  red[threadIdx.x] = s;
  __syncthreads();
  for (int o = 128; o > 0; o >>= 1) {
    if (threadIdx.x < o) red[threadIdx.x] += red[threadIdx.x + o];
    __syncthreads();
  }
  if (threadIdx.x == 0) out[0] = red[0];
}

__global__ __launch_bounds__(256)
void k_final(const u16* __restrict__ Yh, const u16* __restrict__ Yl,
             const float* __restrict__ scal, float* __restrict__ out) {
  __shared__ float red[256];
  float s = 0.f;
  for (int i = threadIdx.x; i < D_DIM; i += 256) {
    size_t d = (size_t)i * (D_DIM + 1);
    s += bf2f(Yh[d]) + bf2f(Yl[d]);
  }
  red[threadIdx.x] = s;
  __syncthreads();
  for (int o = 128; o > 0; o >>= 1) {
    if (threadIdx.x < o) red[threadIdx.x] += red[threadIdx.x + o];
    __syncthreads();
  }
  if (threadIdx.x == 0) {
    float sqrtc = sqrtf(sqrtf(scal[0]));
    out[0] = scal[1] + scal[2] - 2.0f * sqrtc * red[0];
  }
}

// ---------------- launch ----------------

extern "C" void kernel_launch(void* const* d_in, const int* in_sizes, int n_in,
                              void* d_out, int out_size, void* d_ws,
                              size_t ws_size, hipStream_t stream) {
  (void)in_sizes; (void)n_in; (void)out_size; (void)ws_size;
  const float* za = (const float*)d_in[0];
  const float* zb = (const float*)d_in[1];
  float* out = (float*)d_out;
  float* ws = (float*)d_ws;

  float* stat = ws;
  float* scal = ws + 4 * D_DIM;
  u16* b[8];
  {
    char* pool = (char*)d_ws + 65536;
    for (int i = 0; i < 8; ++i) b[i] = (u16*)(pool + (size_t)i * 8388608);
  }
#define PH(p) b[2 * (p)]
#define PL(p) b[2 * (p) + 1]
  // z-split scratch: zh spans pair-2's two slots (b[4]+b[5] = 16 MB),
  // zl spans pair-3's (b[6]+b[7] = 16 MB). One input at a time; dead
  // before M (pair2) and Y1 (pair3) are written.
  u16* zh = b[4];
  u16* zl = b[6];

  hipMemsetAsync(ws, 0, (4 * D_DIM + 16) * sizeof(float), stream);

  dim3 blk(256);
  k_colstats<<<dim3(8, 16), blk, 0, stream>>>(za, stat, stat + D_DIM);
  k_colstats<<<dim3(8, 16), blk, 0, stream>>>(zb, stat + 2 * D_DIM,
                                              stat + 3 * D_DIM);
  k_finalize_stats<<<16, blk, 0, stream>>>(stat);

  dim3 gm(32, 16);  // 64-col x 128-row tiles, 512 blocks
  // A = gram(za_hat) -> pair0
  k_zsplit<<<8192, blk, 0, stream>>>(za, stat, stat + D_DIM, zh, zl);
  k_gram_mm<<<gm, blk, 0, stream>>>(zh, zl, PH(0), PL(0));
  // B = gram(zb_hat) -> pair1
  k_zsplit<<<8192, blk, 0, stream>>>(zb, stat + 2 * D_DIM, stat + 3 * D_DIM,
                                     zh, zl);
  k_gram_mm<<<gm, blk, 0, stream>>>(zh, zl, PH(1), PL(1));

  k_trace_hl<<<1, blk, 0, stream>>>(PH(0), PL(0), scal + 1);
  k_trace_hl<<<1, blk, 0, stream>>>(PH(1), PL(1), scal + 2);

  // M = A*B -> pair2 (z-split scratch dead)
  k_mm<0><<<gm, blk, 0, stream>>>(PH(0), PL(0), PH(1), PL(1), PH(2), PL(2),
                                  scal);
  k_frob_hl<<<4096, blk, 0, stream>>>(PH(2), PL(2), scal);
  // T1 -> pair0 (A dead), Z1 -> pair1 (B dead)
  k_t1z1<<<4096, blk, 0, stream>>>(PH(2), PL(2), scal, PH(0), PL(0), PH(1),
                                   PL(1));
  // Y1 = (0.5/c)*M*T1 -> pair3
  k_mm<3><<<gm, blk, 0, stream>>>(PH(2), PL(2), PH(0), PL(0), PH(3), PL(3),
                                  scal);

  int Y = 3, Z = 1, fA = 0, fB = 2;
  for (int it = 2; it <= NS_ITERS; ++it) {
    k_mm<1><<<gm, blk, 0, stream>>>(PH(Z), PL(Z), PH(Y), PL(Y), PH(fA), PL(fA),
                                    scal);
    k_mm<2><<<gm, blk, 0, stream>>>(PH(Y), PL(Y), PH(fA), PL(fA), PH(fB),
                                    PL(fB), scal);
    if (it < NS_ITERS)
      k_mm<2><<<gm, blk, 0, stream>>>(PH(fA), PL(fA), PH(Z), PL(Z), PH(Y),
                                      PL(Y), scal);
    int oy = Y, oz = Z, oa = fA, ob = fB;
    Y = ob;
    Z = oy;
    fA = oz;
    fB = oa;
  }

  k_final<<<1, blk, 0, stream>>>(PH(Y), PL(Y), scal, out);
#undef PH
#undef PL
}